// Round 2
// baseline (493.676 us; speedup 1.0000x reference)
//
#include <hip/hip_runtime.h>

// ---------------------------------------------------------------- constants
#define T_N   262144
#define D_IN  128
#define GAMMA 0.99f
#define EPS_C 0.2f
#define C_GL  0.9405f                 // GAMMA*LMBD
#define HALF_LOG_2PI 0.9189385332f
#define SCALE2 2.8853900817779268f    // 2*log2(e): pre-activation scale for exp2-tanh
#define ST_TPB 8                      // state tiles (32 rows) per block
#define NX_ITERS 4                    // next tiles (64 rows) per block

typedef __attribute__((ext_vector_type(8))) short short8;
typedef __attribute__((ext_vector_type(4))) float f32x4;

__device__ __forceinline__ unsigned short f2bf(float f) {   // RNE (prep only)
  unsigned int u = __float_as_uint(f);
  u += 0x7FFFu + ((u >> 16) & 1u);
  return (unsigned short)(u >> 16);
}
// pack two f32 -> two bf16 (truncate) in ONE v_perm_b32
__device__ __forceinline__ unsigned int pack_bf2(float lo, float hi) {
  return __builtin_amdgcn_perm(__float_as_uint(hi), __float_as_uint(lo), 0x07060302u);
}
__device__ __forceinline__ unsigned short bf_trunc(float f) {
  return (unsigned short)(__float_as_uint(f) >> 16);
}
// a = 2*log2(e)*x (weights pre-scaled); returns tanh(x).
__device__ __forceinline__ float tanh_pre(float a) {
  float e = __builtin_amdgcn_exp2f(a);
  return 1.f - 2.f * __builtin_amdgcn_rcpf(e + 1.f);
}
template <int CTRL>
__device__ __forceinline__ float dpp_add(float p) {
  return p + __int_as_float(__builtin_amdgcn_update_dpp(
                 0, __float_as_int(p), CTRL, 0xF, 0xF, true));
}
// sum over each 16-lane row; total lands at lane%16 == 15
__device__ __forceinline__ float row16_sum(float p) {
  p = dpp_add<0x111>(p); p = dpp_add<0x112>(p);
  p = dpp_add<0x114>(p); p = dpp_add<0x118>(p);
  return p;
}

// ---------------------------------------------------------------- prep:
// Wc1Ts/W1Ts: [H][D] bf16, transposed AND pre-scaled by 2*log2(e).
// H1: [16][256] bf16 actor head (rows0-7 = Wmu^T, 8-15 = Wlv^T). Also zeros accs.
__global__ __launch_bounds__(256) void k_prep(
    const float* __restrict__ Wc1, const float* __restrict__ W1,
    const float* __restrict__ Wmu, const float* __restrict__ Wlv,
    unsigned short* __restrict__ Wc1Ts, unsigned short* __restrict__ W1Ts,
    unsigned short* __restrict__ H1, float* __restrict__ accs) {
  int i = blockIdx.x * 256 + threadIdx.x;
  if (blockIdx.x == 0 && threadIdx.x < 8) ((unsigned int*)accs)[threadIdx.x] = 0u;
  if (i < 32768) {
    int n = i >> 7, k = i & 127;
    Wc1Ts[i] = f2bf(Wc1[k * 256 + n] * SCALE2);
  } else if (i < 65536) {
    int j = i - 32768; int n = j >> 7, k = j & 127;
    W1Ts[j] = f2bf(W1[k * 256 + n] * SCALE2);
  } else if (i < 69632) {
    int j = i - 65536; int h = j >> 8, n = j & 255;
    H1[j] = (h < 8) ? f2bf(Wmu[n * 8 + h]) : f2bf(Wlv[n * 8 + (h - 8)]);
  }
}

// ---------------------------------------------------------------- k_fused:
// 2048 blocks x 512 threads. role = (blockIdx>>3)&1 so roles interleave across
// the 8 XCDs and on each CU (memory-heavy next-blocks overlap compute-heavy
// state-blocks).
//   role 0 (state): 1024 blocks x 8 tiles of 32 rows.
//     waves 0-3 critic(state)->v0 ; waves 4-7 actor hidden -> sh_h;
//     after barrier2: waves 4,5 run the FULL-K head GEMM (K=256, 8 MFMAs) and
//     compute ratio fully in-register (shfl_xor(32) pairs mu/lv; ds_swizzle
//     xor16 folds the two action-halves). 2 barriers/tile (was 3), no sh_hb.
//   role 1 (next): 1024 blocks x 4 tiles of 64 rows; 8 waves = 2 row-halves
//     x 4 col-slices of critic(next_state)->v1. 2 barriers per 64 rows.
__global__ __launch_bounds__(512, 4) void k_fused(
    const float* __restrict__ state, const float* __restrict__ next_state,
    const float* __restrict__ action, const float* __restrict__ beta_lp,
    const unsigned short* __restrict__ Wc1Ts, const unsigned short* __restrict__ W1Ts,
    const unsigned short* __restrict__ H1,
    const float* __restrict__ bc1, const float* __restrict__ b1,
    const float* __restrict__ Wc2, const float* __restrict__ bc2,
    const float* __restrict__ bmu, const float* __restrict__ blv,
    float* __restrict__ v0out, float* __restrict__ v1out,
    float* __restrict__ ratio) {
  const int tid  = threadIdx.x;
  const int lane = tid & 63;
  const int wv   = tid >> 6;          // 0..7
  const int c    = lane & 15;
  const int quad = lane >> 4;

  const int bid  = blockIdx.x;
  const int grp  = bid >> 3, xcd = bid & 7;
  const int role = grp & 1;                  // 0 = state, 1 = next
  const int rid  = (grp >> 1) * 8 + xcd;     // 0..1023 within role

  // LDS union: state uses sh_x[32][136] + sh_h[32][264] + sh_v[32][4] = 26112 B
  //            next  uses sh_x[64][136] + sh_v2[64][4]               = 18432 B
  __shared__ __align__(16) char smem[26624];
  unsigned short* sh_x  = (unsigned short*)smem;
  unsigned short* sh_h  = (unsigned short*)(smem + 8704);
  float*          sh_v  = (float*)(smem + 25600);
  float*          sh_v2 = (float*)(smem + 17408);

  if (role == 0) {
    // ================= STATE path =================
    const int rw = wv >> 2;           // 0 critic, 1 actor
    const int wl = wv & 3;
    const unsigned short* WT = rw ? W1Ts : Wc1Ts;
    const float* bias = rw ? b1 : bc1;

    short8 bfrag[4][4];
    float bias_c[4], wc2_c[4];
#pragma unroll
    for (int ct = 0; ct < 4; ++ct) {
      int n = wl * 64 + ct * 16 + c;
      bias_c[ct] = bias[n] * SCALE2;
      wc2_c[ct]  = Wc2[n];
#pragma unroll
      for (int ki = 0; ki < 4; ++ki)
        bfrag[ct][ki] = *(const short8*)(WT + n * 128 + ki * 32 + quad * 8);
    }
    const float vbias = bc2[0];
    const int q2 = quad & 1;          // head lanes: a-group (0..3 / 4..7)

    const int t0 = rid * ST_TPB;
    float4 rbuf[2];
    {
      const float4* Xv = (const float4*)(state + (size_t)t0 * 32 * D_IN);
      rbuf[0] = Xv[tid]; rbuf[1] = Xv[tid + 512];
    }

    for (int i = 0; i < ST_TPB; ++i) {
      const int r0 = (t0 + i) * 32;

      // ---- stage regs -> LDS bf16
#pragma unroll
      for (int j = 0; j < 2; ++j) {
        int e4 = tid + j * 512;
        int row = e4 >> 5, c4 = e4 & 31;
        uint2 u;
        u.x = pack_bf2(rbuf[j].x, rbuf[j].y);
        u.y = pack_bf2(rbuf[j].z, rbuf[j].w);
        *(uint2*)(&sh_x[row * 136 + c4 * 4]) = u;
      }
      __syncthreads();                            // barrier1

      if (i + 1 < ST_TPB) {
        const float4* Xv2 = (const float4*)(state + (size_t)(r0 + 32) * D_IN);
        rbuf[0] = Xv2[tid]; rbuf[1] = Xv2[tid + 512];
      }

      if (rw == 0) {
        // ---- critic GEMM + fused head
#pragma unroll
        for (int rt = 0; rt < 2; ++rt) {
          f32x4 acc[4];
#pragma unroll
          for (int ct = 0; ct < 4; ++ct) acc[ct] = (f32x4){0.f, 0.f, 0.f, 0.f};
#pragma unroll
          for (int ki = 0; ki < 4; ++ki) {
            short8 a = *(const short8*)(&sh_x[(rt * 16 + c) * 136 + ki * 32 + quad * 8]);
#pragma unroll
            for (int ct = 0; ct < 4; ++ct)
              acc[ct] = __builtin_amdgcn_mfma_f32_16x16x32_bf16(a, bfrag[ct][ki], acc[ct], 0, 0, 0);
          }
#pragma unroll
          for (int r = 0; r < 4; ++r) {
            float p = 0.f;
#pragma unroll
            for (int ct = 0; ct < 4; ++ct)
              p += tanh_pre(acc[ct][r] + bias_c[ct]) * wc2_c[ct];
            p = row16_sum(p);
            if (c == 15) sh_v[(rt * 16 + quad * 4 + r) * 4 + wl] = p;
          }
        }
      } else {
        // ---- actor GEMM -> sh_h
#pragma unroll
        for (int rt = 0; rt < 2; ++rt) {
          f32x4 acc[4];
#pragma unroll
          for (int ct = 0; ct < 4; ++ct) acc[ct] = (f32x4){0.f, 0.f, 0.f, 0.f};
#pragma unroll
          for (int ki = 0; ki < 4; ++ki) {
            short8 a = *(const short8*)(&sh_x[(rt * 16 + c) * 136 + ki * 32 + quad * 8]);
#pragma unroll
            for (int ct = 0; ct < 4; ++ct)
              acc[ct] = __builtin_amdgcn_mfma_f32_16x16x32_bf16(a, bfrag[ct][ki], acc[ct], 0, 0, 0);
          }
#pragma unroll
          for (int ct = 0; ct < 4; ++ct) {
            int col = wl * 64 + ct * 16 + c;
#pragma unroll
            for (int r = 0; r < 4; ++r) {
              int row = rt * 16 + quad * 4 + r;
              sh_h[row * 264 + col] = bf_trunc(tanh_pre(acc[ct][r] + bias_c[ct]));
            }
          }
        }
      }
      __syncthreads();                            // barrier2

      if (rw == 0) {
        if (tid < 32)
          v0out[r0 + tid] = sh_v[tid * 4] + sh_v[tid * 4 + 1] + sh_v[tid * 4 + 2] +
                            sh_v[tid * 4 + 3] + vbias;
      } else if (wl < 2) {
        // ---- head GEMM over FULL K=256 for 16-row subtile st = wl,
        //      then in-register ratio epilogue (no sh_hb, no barrier3).
        const int st = wl;
        const int rrow = r0 + st * 16 + c;
        float4 act4 = *(const float4*)(action  + rrow * 8 + q2 * 4);
        float4 bt4  = *(const float4*)(beta_lp + rrow * 8 + q2 * 4);

        f32x4 acc2 = (f32x4){0.f, 0.f, 0.f, 0.f};
#pragma unroll
        for (int k2 = 0; k2 < 8; ++k2) {
          int kofs = k2 * 32 + quad * 8;
          short8 a2 = *(const short8*)(H1 + c * 256 + kofs);
          short8 b2 = *(const short8*)(&sh_h[(st * 16 + c) * 264 + kofs]);
          acc2 = __builtin_amdgcn_mfma_f32_16x16x32_bf16(a2, b2, acc2, 0, 0, 0);
        }
        // D-layout: out = quad*4+r (0-7 mu, 8-15 lv), sample = c.
        // quads 0,1 hold mu; matching lv sits at lane+32 -> shfl_xor(32).
        float4 bmu4 = ((const float4*)bmu)[q2];
        float4 blv4 = ((const float4*)blv)[q2];
        float sum = 0.f;
#pragma unroll
        for (int r = 0; r < 4; ++r) {
          float lv = __shfl_xor(acc2[r], 32) + ((const float*)&blv4)[r];
          float mu = acc2[r] + ((const float*)&bmu4)[r];
          float d  = ((const float*)&act4)[r] - mu;
          sum += -0.5f * d * d * __expf(-lv) - 0.5f * lv - HALF_LOG_2PI -
                 ((const float*)&bt4)[r];
        }
        // fold a-halves: quad0 (a0-3) + quad1 (a4-7), same sample c
        sum += __int_as_float(
            __builtin_amdgcn_ds_swizzle(__float_as_int(sum), 0x401F));
        if (quad == 0) ratio[r0 + st * 16 + c] = __expf(sum);
      }
      // waves 6,7 + critic waves 1-3 fall through to next iteration's staging
    }
  } else {
    // ================= NEXT path (critic only, 64-row tiles) =================
    const int wg = wv >> 2;           // row half
    const int wl = wv & 3;            // 64-col slice

    short8 bfrag[4][4];
    float bias_c[4], wc2_c[4];
#pragma unroll
    for (int ct = 0; ct < 4; ++ct) {
      int n = wl * 64 + ct * 16 + c;
      bias_c[ct] = bc1[n] * SCALE2;
      wc2_c[ct]  = Wc2[n];
#pragma unroll
      for (int ki = 0; ki < 4; ++ki)
        bfrag[ct][ki] = *(const short8*)(Wc1Ts + n * 128 + ki * 32 + quad * 8);
    }
    const float vbias = bc2[0];

    const int t0 = rid * NX_ITERS;
    float4 rbuf[4];
    {
      const float4* Xv = (const float4*)(next_state + (size_t)t0 * 64 * D_IN);
#pragma unroll
      for (int j = 0; j < 4; ++j) rbuf[j] = Xv[tid + j * 512];
    }

    for (int i = 0; i < NX_ITERS; ++i) {
      const int r0 = (t0 + i) * 64;
#pragma unroll
      for (int j = 0; j < 4; ++j) {
        int e4 = tid + j * 512;
        int row = e4 >> 5, c4 = e4 & 31;
        uint2 u;
        u.x = pack_bf2(rbuf[j].x, rbuf[j].y);
        u.y = pack_bf2(rbuf[j].z, rbuf[j].w);
        *(uint2*)(&sh_x[row * 136 + c4 * 4]) = u;
      }
      __syncthreads();                            // barrier1

      if (i + 1 < NX_ITERS) {
        const float4* Xv2 = (const float4*)(next_state + (size_t)(r0 + 64) * D_IN);
#pragma unroll
        for (int j = 0; j < 4; ++j) rbuf[j] = Xv2[tid + j * 512];
      }

#pragma unroll
      for (int rt = 0; rt < 2; ++rt) {
        f32x4 acc[4];
#pragma unroll
        for (int ct = 0; ct < 4; ++ct) acc[ct] = (f32x4){0.f, 0.f, 0.f, 0.f};
#pragma unroll
        for (int ki = 0; ki < 4; ++ki) {
          short8 a = *(const short8*)(&sh_x[(wg * 32 + rt * 16 + c) * 136 + ki * 32 + quad * 8]);
#pragma unroll
          for (int ct = 0; ct < 4; ++ct)
            acc[ct] = __builtin_amdgcn_mfma_f32_16x16x32_bf16(a, bfrag[ct][ki], acc[ct], 0, 0, 0);
        }
#pragma unroll
        for (int r = 0; r < 4; ++r) {
          float p = 0.f;
#pragma unroll
          for (int ct = 0; ct < 4; ++ct)
            p += tanh_pre(acc[ct][r] + bias_c[ct]) * wc2_c[ct];
          p = row16_sum(p);
          if (c == 15) sh_v2[(wg * 32 + rt * 16 + quad * 4 + r) * 4 + wl] = p;
        }
      }
      __syncthreads();                            // barrier2

      if (tid < 64)
        v1out[r0 + tid] = sh_v2[tid * 4] + sh_v2[tid * 4 + 1] + sh_v2[tid * 4 + 2] +
                          sh_v2[tid * 4 + 3] + vbias;
    }
  }
}

// ---------------------------------------------------------------- GAE + losses, ONE kernel:
// 256 blocks (== CU count -> guaranteed co-resident; software grid barrier via
// device-scope counters). Each block: 1024 own elems + 1024 lookahead
// (c^1024 ~ 5e-28 -> exact truncation in fp32). adv stays in registers.
__global__ __launch_bounds__(256) void k_gae2(
    const float* __restrict__ reward, const float* __restrict__ v0,
    const float* __restrict__ v1, const float* __restrict__ ratio,
    float* __restrict__ accs, float* __restrict__ out) {
  const int j = blockIdx.x, k = threadIdx.x;
  const int base = j * 1024 + k * 8;
  unsigned int* cnt1 = (unsigned int*)accs + 4;
  unsigned int* cnt2 = (unsigned int*)accs + 5;

  float d[8];
  float s = 0.f, w = 1.f;
#pragma unroll
  for (int i = 0; i < 8; ++i) {
    int idx = base + i;
    float dd = 0.f;
    if (idx < T_N) dd = reward[idx] + GAMMA * v1[idx] - v0[idx];
    d[i] = dd;
    s += w * dd;
    w *= C_GL;
  }
  const float W8 = w;
  __shared__ float Ss[256], Sw[256];
  __shared__ float sh_stats[2];
  Ss[k] = s; Sw[k] = W8;
  __syncthreads();
  for (int st = 1; st < 256; st <<= 1) {
    bool has = (k + st) < 256;
    float ns = 0.f, nw = 0.f;
    if (has) { ns = Ss[k] + Sw[k] * Ss[k + st]; nw = Sw[k] * Sw[k + st]; }
    __syncthreads();
    if (has) { Ss[k] = ns; Sw[k] = nw; }
    __syncthreads();
  }
  float g = (k < 255) ? Ss[k + 1] : 0.f;
  float adv[8];
  float sa = 0.f, sq = 0.f;
  if (k < 128) {
#pragma unroll
    for (int i = 7; i >= 0; --i) {
      g = d[i] + C_GL * g;
      float a = g - v0[base + i];
      adv[i] = a;
      sa += a; sq += a * a;
    }
  }
  __syncthreads();
  Ss[k] = sa; Sw[k] = sq;
  __syncthreads();
  for (int off = 128; off > 0; off >>= 1) {
    if (k < off) { Ss[k] += Ss[k + off]; Sw[k] += Sw[k + off]; }
    __syncthreads();
  }
  if (k == 0) {
    atomicAdd(&accs[0], Ss[0]);                 // Σ adv
    atomicAdd(&accs[1], Sw[0]);                 // Σ adv² (= critic_loss)
    __hip_atomic_fetch_add(cnt1, 1u, __ATOMIC_RELEASE, __HIP_MEMORY_SCOPE_AGENT);
    // ---- software grid barrier (256 blocks co-resident on 256 CUs)
    while (__hip_atomic_load(cnt1, __ATOMIC_ACQUIRE, __HIP_MEMORY_SCOPE_AGENT) < 256u)
      __builtin_amdgcn_s_sleep(4);
    sh_stats[0] = __hip_atomic_load(&accs[0], __ATOMIC_RELAXED, __HIP_MEMORY_SCOPE_AGENT);
    sh_stats[1] = __hip_atomic_load(&accs[1], __ATOMIC_RELAXED, __HIP_MEMORY_SCOPE_AGENT);
  }
  __syncthreads();

  const float sum  = sh_stats[0];
  const float cl   = sh_stats[1];
  const float mean = sum * (1.f / (float)T_N);
  const float var  = (cl - sum * mean) / (float)(T_N - 1);
  const float inv  = 1.f / (sqrtf(var) + 1e-7f);
  float sl = 0.f;
  if (k < 128) {
#pragma unroll
    for (int i = 0; i < 8; ++i) {
      float a = (adv[i] - mean) * inv;
      float r = ratio[base + i];
      float rc = fminf(fmaxf(r, 1.f - EPS_C), 1.f + EPS_C);
      sl += -fminf(r * a, rc * a);
    }
  }
  __syncthreads();
  Ss[k] = sl;
  __syncthreads();
  for (int off = 128; off > 0; off >>= 1) {
    if (k < off) Ss[k] += Ss[k + off];
    __syncthreads();
  }
  if (k == 0) {
    atomicAdd(&accs[2], Ss[0]);                 // actor_loss
    unsigned int old = __hip_atomic_fetch_add(cnt2, 1u, __ATOMIC_ACQ_REL,
                                              __HIP_MEMORY_SCOPE_AGENT);
    if (old == 255u) {
      float al = __hip_atomic_load(&accs[2], __ATOMIC_RELAXED, __HIP_MEMORY_SCOPE_AGENT);
      out[0] = al + cl;                         // actor_loss + critic_loss
    }
  }
}

// ---------------------------------------------------------------- launch
extern "C" void kernel_launch(void* const* d_in, const int* in_sizes, int n_in,
                              void* d_out, int out_size, void* d_ws, size_t ws_size,
                              hipStream_t stream) {
  const float* state      = (const float*)d_in[0];
  const float* next_state = (const float*)d_in[1];
  const float* action     = (const float*)d_in[2];
  const float* beta_lp    = (const float*)d_in[3];
  const float* reward     = (const float*)d_in[4];
  const float* W1   = (const float*)d_in[5];
  const float* b1   = (const float*)d_in[6];
  const float* Wmu  = (const float*)d_in[7];
  const float* bmu  = (const float*)d_in[8];
  const float* Wlv  = (const float*)d_in[9];
  const float* blv  = (const float*)d_in[10];
  const float* Wc1  = (const float*)d_in[11];
  const float* bc1  = (const float*)d_in[12];
  const float* Wc2  = (const float*)d_in[13];
  const float* bc2  = (const float*)d_in[14];

  char* ws = (char*)d_ws;
  size_t o = 0;
  unsigned short* Wc1Ts = (unsigned short*)(ws + o); o += 65536;
  unsigned short* W1Ts  = (unsigned short*)(ws + o); o += 65536;
  unsigned short* H1    = (unsigned short*)(ws + o); o += 8192;
  float* v0    = (float*)(ws + o); o += (size_t)T_N * 4;
  float* v1    = (float*)(ws + o); o += (size_t)T_N * 4;
  float* ratio = (float*)(ws + o); o += (size_t)T_N * 4;
  float* accs  = (float*)(ws + o); o += 256;

  k_prep<<<272, 256, 0, stream>>>(Wc1, W1, Wmu, Wlv, Wc1Ts, W1Ts, H1, accs);

  k_fused<<<2048, 512, 0, stream>>>(
      state, next_state, action, beta_lp, Wc1Ts, W1Ts, H1,
      bc1, b1, Wc2, bc2, bmu, blv, v0, v1, ratio);

  k_gae2<<<256, 256, 0, stream>>>(reward, v0, v1, ratio, accs, (float*)d_out);
}

// Round 4
// 444.950 us; speedup vs baseline: 1.1095x; 1.1095x over previous
//
#include <hip/hip_runtime.h>

// ---------------------------------------------------------------- constants
#define T_N   262144
#define D_IN  128
#define GAMMA 0.99f
#define EPS_C 0.2f
#define C_GL  0.9405f                 // GAMMA*LMBD
#define HALF_LOG_2PI 0.9189385332f
#define SCALE2 2.8853900817779268f    // 2*log2(e): pre-activation scale for exp2-tanh
#define ST_TPB 8                      // k_state tiles/block -> 1024 blocks
#define NX_TPB 4                      // k_next tiles/block  -> 2048 blocks

typedef __attribute__((ext_vector_type(8))) short short8;
typedef __attribute__((ext_vector_type(4))) float f32x4;

__device__ __forceinline__ unsigned short f2bf(float f) {   // RNE (prep only)
  unsigned int u = __float_as_uint(f);
  u += 0x7FFFu + ((u >> 16) & 1u);
  return (unsigned short)(u >> 16);
}
// pack two f32 -> two bf16 (truncate) in ONE v_perm_b32
__device__ __forceinline__ unsigned int pack_bf2(float lo, float hi) {
  return __builtin_amdgcn_perm(__float_as_uint(hi), __float_as_uint(lo), 0x07060302u);
}
__device__ __forceinline__ unsigned short bf_trunc(float f) {
  return (unsigned short)(__float_as_uint(f) >> 16);
}
// a = 2*log2(e)*x (weights pre-scaled); returns tanh(x).
__device__ __forceinline__ float tanh_pre(float a) {
  float e = __builtin_amdgcn_exp2f(a);
  return 1.f - 2.f * __builtin_amdgcn_rcpf(e + 1.f);
}
template <int CTRL>
__device__ __forceinline__ float dpp_add(float p) {
  return p + __int_as_float(__builtin_amdgcn_update_dpp(
                 0, __float_as_int(p), CTRL, 0xF, 0xF, true));
}
// sum over each 16-lane row; total lands at lane%16 == 15
__device__ __forceinline__ float row16_sum(float p) {
  p = dpp_add<0x111>(p); p = dpp_add<0x112>(p);
  p = dpp_add<0x114>(p); p = dpp_add<0x118>(p);
  return p;
}

// ---------------------------------------------------------------- prep:
// Wc1Ts/W1Ts: [H][D] bf16, transposed AND pre-scaled by 2*log2(e).
// H1: [16][256] bf16 actor head (rows0-7 = Wmu^T, 8-15 = Wlv^T). Also zeros accs.
__global__ __launch_bounds__(256) void k_prep(
    const float* __restrict__ Wc1, const float* __restrict__ W1,
    const float* __restrict__ Wmu, const float* __restrict__ Wlv,
    unsigned short* __restrict__ Wc1Ts, unsigned short* __restrict__ W1Ts,
    unsigned short* __restrict__ H1, float* __restrict__ accs) {
  int i = blockIdx.x * 256 + threadIdx.x;
  if (blockIdx.x == 0 && threadIdx.x < 8) ((unsigned int*)accs)[threadIdx.x] = 0u;
  if (i < 32768) {
    int n = i >> 7, k = i & 127;
    Wc1Ts[i] = f2bf(Wc1[k * 256 + n] * SCALE2);
  } else if (i < 65536) {
    int j = i - 32768; int n = j >> 7, k = j & 127;
    W1Ts[j] = f2bf(W1[k * 256 + n] * SCALE2);
  } else if (i < 69632) {
    int j = i - 65536; int h = j >> 8, n = j & 255;
    H1[j] = (h < 8) ? f2bf(Wmu[n * 8 + h]) : f2bf(Wlv[n * 8 + (h - 8)]);
  }
}

// ---------------------------------------------------------------- k_state:
// 1024 blocks x 512 threads, software-pipelined to ONE barrier per tile.
// Iter i: stage tile i+1 -> sh_x[(i+1)&1]; GEMM tile i (critic -> sh_v[i&1],
// actor -> sh_h[i&1]); head GEMM + ratio + v0-write for tile i-1 from the
// (i-1)&1 buffers (validated in-register epilogue: shfl_xor32 mu/lv pairing,
// ds_swizzle 0x401F a-half fold). One __syncthreads at iter end suffices:
// each buffer's read completes before the barrier, its overwrite happens after.
__global__ __launch_bounds__(512, 4) void k_state(
    const float* __restrict__ state,
    const float* __restrict__ action, const float* __restrict__ beta_lp,
    const unsigned short* __restrict__ Wc1Ts, const unsigned short* __restrict__ W1Ts,
    const unsigned short* __restrict__ H1,
    const float* __restrict__ bc1, const float* __restrict__ b1,
    const float* __restrict__ Wc2, const float* __restrict__ bc2,
    const float* __restrict__ bmu, const float* __restrict__ blv,
    float* __restrict__ v0out, float* __restrict__ ratio) {
  const int tid  = threadIdx.x;
  const int lane = tid & 63;
  const int wv   = tid >> 6;          // 0..7
  const int rw   = wv >> 2;           // 0 = critic, 1 = actor
  const int wl   = wv & 3;            // slice within role
  const int c    = lane & 15;
  const int quad = lane >> 4;
  const int q2   = quad & 1;

  __shared__ unsigned short sh_x[2][32 * 136];   // 17.0 KB
  __shared__ unsigned short sh_h[2][32 * 264];   // 33.0 KB
  __shared__ float          sh_v[2][32 * 4];     //  1.0 KB

  const unsigned short* WT = rw ? W1Ts : Wc1Ts;
  const float* bias = rw ? b1 : bc1;

  short8 bfrag[4][4];
  float bias_c[4], wc2_c[4];
#pragma unroll
  for (int ct = 0; ct < 4; ++ct) {
    int n = wl * 64 + ct * 16 + c;
    bias_c[ct] = bias[n] * SCALE2;
    wc2_c[ct]  = Wc2[n];
#pragma unroll
    for (int ki = 0; ki < 4; ++ki)
      bfrag[ct][ki] = *(const short8*)(WT + n * 128 + ki * 32 + quad * 8);
  }
  const float vbias = bc2[0];

  const int t0 = blockIdx.x * ST_TPB;

  // ---- prologue: stage tile 0, preload rbuf with tile 1
  float4 rbuf[2];
  {
    const float4* Xv = (const float4*)(state + (size_t)t0 * 32 * D_IN);
    rbuf[0] = Xv[tid]; rbuf[1] = Xv[tid + 512];
#pragma unroll
    for (int j = 0; j < 2; ++j) {
      int e4 = tid + j * 512;
      int row = e4 >> 5, c4 = e4 & 31;
      uint2 u;
      u.x = pack_bf2(rbuf[j].x, rbuf[j].y);
      u.y = pack_bf2(rbuf[j].z, rbuf[j].w);
      *(uint2*)(&sh_x[0][row * 136 + c4 * 4]) = u;
    }
    const float4* Xv1 = (const float4*)(state + (size_t)(t0 + 1) * 32 * D_IN);
    rbuf[0] = Xv1[tid]; rbuf[1] = Xv1[tid + 512];
  }
  __syncthreads();

  for (int i = 0; i < ST_TPB; ++i) {
    const int r0  = (t0 + i) * 32;
    const int r0p = r0 - 32;                    // tile i-1 rows

    // ---- issue head-input loads for tile i-1 early (hidden under GEMM)
    float4 act4, bt4;
    const bool headw = (rw == 1) && (wl < 2);
    if (headw && i > 0) {
      int rrow = r0p + wl * 16 + c;
      act4 = *(const float4*)(action  + rrow * 8 + q2 * 4);
      bt4  = *(const float4*)(beta_lp + rrow * 8 + q2 * 4);
    }

    // ---- stage tile i+1 -> sh_x[(i+1)&1]; then prefetch tile i+2
    if (i + 1 < ST_TPB) {
#pragma unroll
      for (int j = 0; j < 2; ++j) {
        int e4 = tid + j * 512;
        int row = e4 >> 5, c4 = e4 & 31;
        uint2 u;
        u.x = pack_bf2(rbuf[j].x, rbuf[j].y);
        u.y = pack_bf2(rbuf[j].z, rbuf[j].w);
        *(uint2*)(&sh_x[(i + 1) & 1][row * 136 + c4 * 4]) = u;
      }
      if (i + 2 < ST_TPB) {
        const float4* Xv2 = (const float4*)(state + (size_t)(r0 + 64) * D_IN);
        rbuf[0] = Xv2[tid]; rbuf[1] = Xv2[tid + 512];
      }
    }

    // ---- GEMM tile i
    const unsigned short* xb = sh_x[i & 1];
    if (rw == 0) {
#pragma unroll
      for (int rt = 0; rt < 2; ++rt) {
        f32x4 acc[4];
#pragma unroll
        for (int ct = 0; ct < 4; ++ct) acc[ct] = (f32x4){0.f, 0.f, 0.f, 0.f};
#pragma unroll
        for (int ki = 0; ki < 4; ++ki) {
          short8 a = *(const short8*)(&xb[(rt * 16 + c) * 136 + ki * 32 + quad * 8]);
#pragma unroll
          for (int ct = 0; ct < 4; ++ct)
            acc[ct] = __builtin_amdgcn_mfma_f32_16x16x32_bf16(a, bfrag[ct][ki], acc[ct], 0, 0, 0);
        }
#pragma unroll
        for (int r = 0; r < 4; ++r) {
          float p = 0.f;
#pragma unroll
          for (int ct = 0; ct < 4; ++ct)
            p += tanh_pre(acc[ct][r] + bias_c[ct]) * wc2_c[ct];
          p = row16_sum(p);
          if (c == 15) sh_v[i & 1][(rt * 16 + quad * 4 + r) * 4 + wl] = p;
        }
      }
    } else {
#pragma unroll
      for (int rt = 0; rt < 2; ++rt) {
        f32x4 acc[4];
#pragma unroll
        for (int ct = 0; ct < 4; ++ct) acc[ct] = (f32x4){0.f, 0.f, 0.f, 0.f};
#pragma unroll
        for (int ki = 0; ki < 4; ++ki) {
          short8 a = *(const short8*)(&xb[(rt * 16 + c) * 136 + ki * 32 + quad * 8]);
#pragma unroll
          for (int ct = 0; ct < 4; ++ct)
            acc[ct] = __builtin_amdgcn_mfma_f32_16x16x32_bf16(a, bfrag[ct][ki], acc[ct], 0, 0, 0);
        }
#pragma unroll
        for (int ct = 0; ct < 4; ++ct) {
          int col = wl * 64 + ct * 16 + c;
#pragma unroll
          for (int r = 0; r < 4; ++r) {
            int row = rt * 16 + quad * 4 + r;
            sh_h[i & 1][row * 264 + col] = bf_trunc(tanh_pre(acc[ct][r] + bias_c[ct]));
          }
        }
      }
    }

    // ---- head + v0 for tile i-1 (reads (i-1)&1 buffers, written last iter)
    if (i > 0) {
      if (headw) {
        const int st = wl;
        const unsigned short* hb = sh_h[(i - 1) & 1];
        f32x4 acc2 = (f32x4){0.f, 0.f, 0.f, 0.f};
#pragma unroll
        for (int k2 = 0; k2 < 8; ++k2) {
          int kofs = k2 * 32 + quad * 8;
          short8 a2 = *(const short8*)(H1 + c * 256 + kofs);
          short8 b2 = *(const short8*)(&hb[(st * 16 + c) * 264 + kofs]);
          acc2 = __builtin_amdgcn_mfma_f32_16x16x32_bf16(a2, b2, acc2, 0, 0, 0);
        }
        float4 bmu4 = ((const float4*)bmu)[q2];
        float4 blv4 = ((const float4*)blv)[q2];
        float sum = 0.f;
#pragma unroll
        for (int r = 0; r < 4; ++r) {
          float lv = __shfl_xor(acc2[r], 32) + ((const float*)&blv4)[r];
          float mu = acc2[r] + ((const float*)&bmu4)[r];
          float d  = ((const float*)&act4)[r] - mu;
          sum += -0.5f * d * d * __expf(-lv) - 0.5f * lv - HALF_LOG_2PI -
                 ((const float*)&bt4)[r];
        }
        sum += __int_as_float(
            __builtin_amdgcn_ds_swizzle(__float_as_int(sum), 0x401F));
        if (quad == 0) ratio[r0p + st * 16 + c] = __expf(sum);
      } else if (tid < 32) {
        const float* vb = sh_v[(i - 1) & 1];
        v0out[r0p + tid] = vb[tid * 4] + vb[tid * 4 + 1] + vb[tid * 4 + 2] +
                           vb[tid * 4 + 3] + vbias;
      }
    }
    __syncthreads();
  }

  // ---- epilogue: head + v0 for the last tile
  {
    const int r0p = (t0 + ST_TPB - 1) * 32;
    const int p   = (ST_TPB - 1) & 1;
    if ((rw == 1) && (wl < 2)) {
      const int st = wl;
      int rrow = r0p + st * 16 + c;
      float4 act4 = *(const float4*)(action  + rrow * 8 + q2 * 4);
      float4 bt4  = *(const float4*)(beta_lp + rrow * 8 + q2 * 4);
      const unsigned short* hb = sh_h[p];
      f32x4 acc2 = (f32x4){0.f, 0.f, 0.f, 0.f};
#pragma unroll
      for (int k2 = 0; k2 < 8; ++k2) {
        int kofs = k2 * 32 + quad * 8;
        short8 a2 = *(const short8*)(H1 + c * 256 + kofs);
        short8 b2 = *(const short8*)(&hb[(st * 16 + c) * 264 + kofs]);
        acc2 = __builtin_amdgcn_mfma_f32_16x16x32_bf16(a2, b2, acc2, 0, 0, 0);
      }
      float4 bmu4 = ((const float4*)bmu)[q2];
      float4 blv4 = ((const float4*)blv)[q2];
      float sum = 0.f;
#pragma unroll
      for (int r = 0; r < 4; ++r) {
        float lv = __shfl_xor(acc2[r], 32) + ((const float*)&blv4)[r];
        float mu = acc2[r] + ((const float*)&bmu4)[r];
        float d  = ((const float*)&act4)[r] - mu;
        sum += -0.5f * d * d * __expf(-lv) - 0.5f * lv - HALF_LOG_2PI -
               ((const float*)&bt4)[r];
      }
      sum += __int_as_float(
          __builtin_amdgcn_ds_swizzle(__float_as_int(sum), 0x401F));
      if (quad == 0) ratio[r0p + st * 16 + c] = __expf(sum);
    } else if (tid < 32) {
      const float* vb = sh_v[p];
      v0out[r0p + tid] = vb[tid * 4] + vb[tid * 4 + 1] + vb[tid * 4 + 2] +
                         vb[tid * 4 + 3] + vbias;
    }
  }
}

// ---------------------------------------------------------------- k_next:
// critic(next_state) -> v1. 2048 blocks x 256 threads, pipelined to ONE
// barrier per tile (v1-write for tile i-1 overlaps GEMM of tile i).
__global__ __launch_bounds__(256, 4) void k_next(
    const float* __restrict__ next_state,
    const unsigned short* __restrict__ Wc1Ts,
    const float* __restrict__ bc1, const float* __restrict__ Wc2,
    const float* __restrict__ bc2, float* __restrict__ v1out) {
  const int tid = threadIdx.x;
  const int lane = tid & 63;
  const int wv   = tid >> 6;
  const int c    = lane & 15;
  const int quad = lane >> 4;

  __shared__ unsigned short sh_x[2][32 * 136];
  __shared__ float          sh_v[2][32 * 4];

  short8 bfrag[4][4];
  float bias_c[4], wc2_c[4];
#pragma unroll
  for (int ct = 0; ct < 4; ++ct) {
    int n = wv * 64 + ct * 16 + c;
    bias_c[ct] = bc1[n] * SCALE2;
    wc2_c[ct]  = Wc2[n];
#pragma unroll
    for (int ki = 0; ki < 4; ++ki)
      bfrag[ct][ki] = *(const short8*)(Wc1Ts + n * 128 + ki * 32 + quad * 8);
  }
  const float vbias = bc2[0];

  const int t0 = blockIdx.x * NX_TPB;

  // ---- prologue: stage tile 0, preload rbuf with tile 1
  float4 rbuf[4];
  {
    const float4* Xv = (const float4*)(next_state + (size_t)t0 * 32 * D_IN);
#pragma unroll
    for (int j = 0; j < 4; ++j) rbuf[j] = Xv[tid + j * 256];
#pragma unroll
    for (int j = 0; j < 4; ++j) {
      int e = tid + j * 256;
      int row = e >> 5, c4 = e & 31;
      uint2 u;
      u.x = pack_bf2(rbuf[j].x, rbuf[j].y);
      u.y = pack_bf2(rbuf[j].z, rbuf[j].w);
      *(uint2*)(&sh_x[0][row * 136 + c4 * 4]) = u;
    }
    const float4* Xv1 = (const float4*)(next_state + (size_t)(t0 + 1) * 32 * D_IN);
#pragma unroll
    for (int j = 0; j < 4; ++j) rbuf[j] = Xv1[tid + j * 256];
  }
  __syncthreads();

  for (int i = 0; i < NX_TPB; ++i) {
    const int r0  = (t0 + i) * 32;
    const int r0p = r0 - 32;

    // ---- stage tile i+1; prefetch tile i+2
    if (i + 1 < NX_TPB) {
#pragma unroll
      for (int j = 0; j < 4; ++j) {
        int e = tid + j * 256;
        int row = e >> 5, c4 = e & 31;
        uint2 u;
        u.x = pack_bf2(rbuf[j].x, rbuf[j].y);
        u.y = pack_bf2(rbuf[j].z, rbuf[j].w);
        *(uint2*)(&sh_x[(i + 1) & 1][row * 136 + c4 * 4]) = u;
      }
      if (i + 2 < NX_TPB) {
        const float4* Xv2 = (const float4*)(next_state + (size_t)(r0 + 64) * D_IN);
#pragma unroll
        for (int j = 0; j < 4; ++j) rbuf[j] = Xv2[tid + j * 256];
      }
    }

    // ---- GEMM tile i
    const unsigned short* xb = sh_x[i & 1];
#pragma unroll
    for (int rt = 0; rt < 2; ++rt) {
      f32x4 acc[4];
#pragma unroll
      for (int ct = 0; ct < 4; ++ct) acc[ct] = (f32x4){0.f, 0.f, 0.f, 0.f};
#pragma unroll
      for (int ki = 0; ki < 4; ++ki) {
        short8 a = *(const short8*)(&xb[(rt * 16 + c) * 136 + ki * 32 + quad * 8]);
#pragma unroll
        for (int ct = 0; ct < 4; ++ct)
          acc[ct] = __builtin_amdgcn_mfma_f32_16x16x32_bf16(a, bfrag[ct][ki], acc[ct], 0, 0, 0);
      }
#pragma unroll
      for (int r = 0; r < 4; ++r) {
        float p = 0.f;
#pragma unroll
        for (int ct = 0; ct < 4; ++ct)
          p += tanh_pre(acc[ct][r] + bias_c[ct]) * wc2_c[ct];
        p = row16_sum(p);
        if (c == 15) sh_v[i & 1][(rt * 16 + quad * 4 + r) * 4 + wv] = p;
      }
    }

    // ---- v1 write for tile i-1
    if (i > 0 && tid < 32) {
      const float* vb = sh_v[(i - 1) & 1];
      v1out[r0p + tid] = vb[tid * 4] + vb[tid * 4 + 1] + vb[tid * 4 + 2] +
                         vb[tid * 4 + 3] + vbias;
    }
    __syncthreads();
  }
  if (tid < 32) {
    const float* vb = sh_v[(NX_TPB - 1) & 1];
    v1out[(t0 + NX_TPB - 1) * 32 + tid] = vb[tid * 4] + vb[tid * 4 + 1] +
                                          vb[tid * 4 + 2] + vb[tid * 4 + 3] + vbias;
  }
}

// ---------------------------------------------------------------- GAE + losses, ONE kernel:
// 256 blocks (== CU count -> guaranteed co-resident; software grid barrier via
// device-scope counters). Each block: 1024 own elems + 1024 lookahead
// (c^1024 ~ 5e-28 -> exact truncation in fp32). adv stays in registers.
__global__ __launch_bounds__(256) void k_gae2(
    const float* __restrict__ reward, const float* __restrict__ v0,
    const float* __restrict__ v1, const float* __restrict__ ratio,
    float* __restrict__ accs, float* __restrict__ out) {
  const int j = blockIdx.x, k = threadIdx.x;
  const int base = j * 1024 + k * 8;
  unsigned int* cnt1 = (unsigned int*)accs + 4;
  unsigned int* cnt2 = (unsigned int*)accs + 5;

  float d[8];
  float s = 0.f, w = 1.f;
#pragma unroll
  for (int i = 0; i < 8; ++i) {
    int idx = base + i;
    float dd = 0.f;
    if (idx < T_N) dd = reward[idx] + GAMMA * v1[idx] - v0[idx];
    d[i] = dd;
    s += w * dd;
    w *= C_GL;
  }
  const float W8 = w;
  __shared__ float Ss[256], Sw[256];
  __shared__ float sh_stats[2];
  Ss[k] = s; Sw[k] = W8;
  __syncthreads();
  for (int st = 1; st < 256; st <<= 1) {
    bool has = (k + st) < 256;
    float ns = 0.f, nw = 0.f;
    if (has) { ns = Ss[k] + Sw[k] * Ss[k + st]; nw = Sw[k] * Sw[k + st]; }
    __syncthreads();
    if (has) { Ss[k] = ns; Sw[k] = nw; }
    __syncthreads();
  }
  float g = (k < 255) ? Ss[k + 1] : 0.f;
  float adv[8];
  float sa = 0.f, sq = 0.f;
  if (k < 128) {
#pragma unroll
    for (int i = 7; i >= 0; --i) {
      g = d[i] + C_GL * g;
      float a = g - v0[base + i];
      adv[i] = a;
      sa += a; sq += a * a;
    }
  }
  __syncthreads();
  Ss[k] = sa; Sw[k] = sq;
  __syncthreads();
  for (int off = 128; off > 0; off >>= 1) {
    if (k < off) { Ss[k] += Ss[k + off]; Sw[k] += Sw[k + off]; }
    __syncthreads();
  }
  if (k == 0) {
    atomicAdd(&accs[0], Ss[0]);                 // Σ adv
    atomicAdd(&accs[1], Sw[0]);                 // Σ adv² (= critic_loss)
    __hip_atomic_fetch_add(cnt1, 1u, __ATOMIC_RELEASE, __HIP_MEMORY_SCOPE_AGENT);
    // ---- software grid barrier (256 blocks co-resident on 256 CUs)
    while (__hip_atomic_load(cnt1, __ATOMIC_ACQUIRE, __HIP_MEMORY_SCOPE_AGENT) < 256u)
      __builtin_amdgcn_s_sleep(4);
    sh_stats[0] = __hip_atomic_load(&accs[0], __ATOMIC_RELAXED, __HIP_MEMORY_SCOPE_AGENT);
    sh_stats[1] = __hip_atomic_load(&accs[1], __ATOMIC_RELAXED, __HIP_MEMORY_SCOPE_AGENT);
  }
  __syncthreads();

  const float sum  = sh_stats[0];
  const float cl   = sh_stats[1];
  const float mean = sum * (1.f / (float)T_N);
  const float var  = (cl - sum * mean) / (float)(T_N - 1);
  const float inv  = 1.f / (sqrtf(var) + 1e-7f);
  float sl = 0.f;
  if (k < 128) {
#pragma unroll
    for (int i = 0; i < 8; ++i) {
      float a = (adv[i] - mean) * inv;
      float r = ratio[base + i];
      float rc = fminf(fmaxf(r, 1.f - EPS_C), 1.f + EPS_C);
      sl += -fminf(r * a, rc * a);
    }
  }
  __syncthreads();
  Ss[k] = sl;
  __syncthreads();
  for (int off = 128; off > 0; off >>= 1) {
    if (k < off) Ss[k] += Ss[k + off];
    __syncthreads();
  }
  if (k == 0) {
    atomicAdd(&accs[2], Ss[0]);                 // actor_loss
    unsigned int old = __hip_atomic_fetch_add(cnt2, 1u, __ATOMIC_ACQ_REL,
                                              __HIP_MEMORY_SCOPE_AGENT);
    if (old == 255u) {
      float al = __hip_atomic_load(&accs[2], __ATOMIC_RELAXED, __HIP_MEMORY_SCOPE_AGENT);
      out[0] = al + cl;                         // actor_loss + critic_loss
    }
  }
}

// ---------------------------------------------------------------- launch
extern "C" void kernel_launch(void* const* d_in, const int* in_sizes, int n_in,
                              void* d_out, int out_size, void* d_ws, size_t ws_size,
                              hipStream_t stream) {
  const float* state      = (const float*)d_in[0];
  const float* next_state = (const float*)d_in[1];
  const float* action     = (const float*)d_in[2];
  const float* beta_lp    = (const float*)d_in[3];
  const float* reward     = (const float*)d_in[4];
  const float* W1   = (const float*)d_in[5];
  const float* b1   = (const float*)d_in[6];
  const float* Wmu  = (const float*)d_in[7];
  const float* bmu  = (const float*)d_in[8];
  const float* Wlv  = (const float*)d_in[9];
  const float* blv  = (const float*)d_in[10];
  const float* Wc1  = (const float*)d_in[11];
  const float* bc1  = (const float*)d_in[12];
  const float* Wc2  = (const float*)d_in[13];
  const float* bc2  = (const float*)d_in[14];

  char* ws = (char*)d_ws;
  size_t o = 0;
  unsigned short* Wc1Ts = (unsigned short*)(ws + o); o += 65536;
  unsigned short* W1Ts  = (unsigned short*)(ws + o); o += 65536;
  unsigned short* H1    = (unsigned short*)(ws + o); o += 8192;
  float* v0    = (float*)(ws + o); o += (size_t)T_N * 4;
  float* v1    = (float*)(ws + o); o += (size_t)T_N * 4;
  float* ratio = (float*)(ws + o); o += (size_t)T_N * 4;
  float* accs  = (float*)(ws + o); o += 256;

  k_prep<<<272, 256, 0, stream>>>(Wc1, W1, Wmu, Wlv, Wc1Ts, W1Ts, H1, accs);

  k_state<<<(T_N / 32) / ST_TPB, 512, 0, stream>>>(
      state, action, beta_lp, Wc1Ts, W1Ts, H1, bc1, b1, Wc2, bc2, bmu, blv,
      v0, ratio);
  k_next<<<(T_N / 32) / NX_TPB, 256, 0, stream>>>(
      next_state, Wc1Ts, bc1, Wc2, bc2, v1);
  k_gae2<<<256, 256, 0, stream>>>(reward, v0, v1, ratio, accs, (float*)d_out);
}

// Round 7
// 418.791 us; speedup vs baseline: 1.1788x; 1.0625x over previous
//
#include <hip/hip_runtime.h>

// ---------------------------------------------------------------- constants
#define T_N   262144
#define D_IN  128
#define GAMMA 0.99f
#define EPS_C 0.2f
#define C_GL  0.9405f                 // GAMMA*LMBD
#define HALF_LOG_2PI 0.9189385332f
#define SCALE2 2.8853900817779268f    // 2*log2(e): pre-activation scale for exp2-tanh
#define ST_TPB 8                      // k_state tiles/block -> 1024 blocks (4/CU)
#define NX_TPB 4                      // k_next tiles/block  -> 2048 blocks (8/CU)

typedef __attribute__((ext_vector_type(8))) short short8;
typedef __attribute__((ext_vector_type(4))) float f32x4;

__device__ __forceinline__ unsigned short f2bf(float f) {   // RNE (prep only)
  unsigned int u = __float_as_uint(f);
  u += 0x7FFFu + ((u >> 16) & 1u);
  return (unsigned short)(u >> 16);
}
// pack two f32 -> two bf16 (truncate) in ONE v_perm_b32
__device__ __forceinline__ unsigned int pack_bf2(float lo, float hi) {
  return __builtin_amdgcn_perm(__float_as_uint(hi), __float_as_uint(lo), 0x07060302u);
}
__device__ __forceinline__ unsigned short bf_trunc(float f) {
  return (unsigned short)(__float_as_uint(f) >> 16);
}
// a = 2*log2(e)*x (weights pre-scaled); returns tanh(x).
__device__ __forceinline__ float tanh_pre(float a) {
  float e = __builtin_amdgcn_exp2f(a);
  return 1.f - 2.f * __builtin_amdgcn_rcpf(e + 1.f);
}
template <int CTRL>
__device__ __forceinline__ float dpp_add(float p) {
  return p + __int_as_float(__builtin_amdgcn_update_dpp(
                 0, __float_as_int(p), CTRL, 0xF, 0xF, true));
}
// sum over each 16-lane row; total lands at lane%16 == 15
__device__ __forceinline__ float row16_sum(float p) {
  p = dpp_add<0x111>(p); p = dpp_add<0x112>(p);
  p = dpp_add<0x114>(p); p = dpp_add<0x118>(p);
  return p;
}

// ---------------------------------------------------------------- prep:
// Wc1Ts/W1Ts: [H][D] bf16, transposed AND pre-scaled by 2*log2(e).
// H1: [16][256] bf16 actor head (rows0-7 = Wmu^T, 8-15 = Wlv^T). Also zeros accs.
__global__ __launch_bounds__(256) void k_prep(
    const float* __restrict__ Wc1, const float* __restrict__ W1,
    const float* __restrict__ Wmu, const float* __restrict__ Wlv,
    unsigned short* __restrict__ Wc1Ts, unsigned short* __restrict__ W1Ts,
    unsigned short* __restrict__ H1, float* __restrict__ accs) {
  int i = blockIdx.x * 256 + threadIdx.x;
  if (blockIdx.x == 0 && threadIdx.x < 8) ((unsigned int*)accs)[threadIdx.x] = 0u;
  if (i < 32768) {
    int n = i >> 7, k = i & 127;
    Wc1Ts[i] = f2bf(Wc1[k * 256 + n] * SCALE2);
  } else if (i < 65536) {
    int j = i - 32768; int n = j >> 7, k = j & 127;
    W1Ts[j] = f2bf(W1[k * 256 + n] * SCALE2);
  } else if (i < 69632) {
    int j = i - 65536; int h = j >> 8, n = j & 255;
    H1[j] = (h < 8) ? f2bf(Wmu[n * 8 + h]) : f2bf(Wlv[n * 8 + (h - 8)]);
  }
}

// ---------------------------------------------------------------- k_state:
// 1024 blocks x ST_TPB tiles of 32 rows; 512 threads. R0 structure with
// barrier3 REMOVED: after barrier2, critic wave 0 writes v0; actor waves
// 4,5 run the FULL-K (K=256) head GEMM and the in-register ratio epilogue
// (shfl_xor32 mu/lv pairing + ds_swizzle 0x401F a-half fold — validated
// absmax=0 in two prior rounds). 2 barriers/tile, no sh_hb, no 256-thread
// ratio phase. Safety: head reads of sh_h[i] finish before barrier1 of
// iter i+1; sh_h is rewritten only after that barrier.
__global__ __launch_bounds__(512, 4) void k_state(
    const float* __restrict__ state,
    const float* __restrict__ action, const float* __restrict__ beta_lp,
    const unsigned short* __restrict__ Wc1Ts, const unsigned short* __restrict__ W1Ts,
    const unsigned short* __restrict__ H1,
    const float* __restrict__ bc1, const float* __restrict__ b1,
    const float* __restrict__ Wc2, const float* __restrict__ bc2,
    const float* __restrict__ bmu, const float* __restrict__ blv,
    float* __restrict__ v0out, float* __restrict__ ratio) {
  const int tid  = threadIdx.x;
  const int lane = tid & 63;
  const int wv   = tid >> 6;          // 0..7
  const int rw   = wv >> 2;           // 0 = critic, 1 = actor
  const int wl   = wv & 3;            // slice within role
  const int c    = lane & 15;
  const int quad = lane >> 4;
  const int q2   = quad & 1;

  __shared__ unsigned short sh_x[32 * 136];   // 8.5 KB
  __shared__ unsigned short sh_h[32 * 264];   // 16.5 KB
  __shared__ float sh_v[32 * 4];

  const unsigned short* WT = rw ? W1Ts : Wc1Ts;
  const float* bias = rw ? b1 : bc1;

  short8 bfrag[4][4];
  float bias_c[4], wc2_c[4];
#pragma unroll
  for (int ct = 0; ct < 4; ++ct) {
    int n = wl * 64 + ct * 16 + c;
    bias_c[ct] = bias[n] * SCALE2;
    wc2_c[ct]  = Wc2[n];
#pragma unroll
    for (int ki = 0; ki < 4; ++ki)
      bfrag[ct][ki] = *(const short8*)(WT + n * 128 + ki * 32 + quad * 8);
  }
  const float vbias = bc2[0];
  const float4 bmu4 = ((const float4*)bmu)[q2];
  const float4 blv4 = ((const float4*)blv)[q2];

  const int t0 = blockIdx.x * ST_TPB;

  float4 rbuf[2];
  {
    const float4* Xv = (const float4*)(state + (size_t)t0 * 32 * D_IN);
    rbuf[0] = Xv[tid]; rbuf[1] = Xv[tid + 512];
  }

  for (int i = 0; i < ST_TPB; ++i) {
    const int r0 = (t0 + i) * 32;

    // ---- stage regs -> LDS bf16 (perm-truncate: 1 op / 2 elems)
#pragma unroll
    for (int j = 0; j < 2; ++j) {
      int e4 = tid + j * 512;
      int row = e4 >> 5, c4 = e4 & 31;
      uint2 u;
      u.x = pack_bf2(rbuf[j].x, rbuf[j].y);
      u.y = pack_bf2(rbuf[j].z, rbuf[j].w);
      *(uint2*)(&sh_x[row * 136 + c4 * 4]) = u;
    }
    __syncthreads();                            // barrier1

    if (i + 1 < ST_TPB) {
      const float4* Xv2 = (const float4*)(state + (size_t)(r0 + 32) * D_IN);
      rbuf[0] = Xv2[tid]; rbuf[1] = Xv2[tid + 512];
    }

    if (rw == 0) {
      // ---- critic GEMM + fused head
#pragma unroll
      for (int rt = 0; rt < 2; ++rt) {
        f32x4 acc[4];
#pragma unroll
        for (int ct = 0; ct < 4; ++ct) acc[ct] = (f32x4){0.f, 0.f, 0.f, 0.f};
#pragma unroll
        for (int ki = 0; ki < 4; ++ki) {
          short8 a = *(const short8*)(&sh_x[(rt * 16 + c) * 136 + ki * 32 + quad * 8]);
#pragma unroll
          for (int ct = 0; ct < 4; ++ct)
            acc[ct] = __builtin_amdgcn_mfma_f32_16x16x32_bf16(a, bfrag[ct][ki], acc[ct], 0, 0, 0);
        }
#pragma unroll
        for (int r = 0; r < 4; ++r) {
          float p = 0.f;
#pragma unroll
          for (int ct = 0; ct < 4; ++ct)
            p += tanh_pre(acc[ct][r] + bias_c[ct]) * wc2_c[ct];
          p = row16_sum(p);
          if (c == 15) sh_v[(rt * 16 + quad * 4 + r) * 4 + wl] = p;
        }
      }
    } else {
      // ---- actor GEMM -> sh_h
#pragma unroll
      for (int rt = 0; rt < 2; ++rt) {
        f32x4 acc[4];
#pragma unroll
        for (int ct = 0; ct < 4; ++ct) acc[ct] = (f32x4){0.f, 0.f, 0.f, 0.f};
#pragma unroll
        for (int ki = 0; ki < 4; ++ki) {
          short8 a = *(const short8*)(&sh_x[(rt * 16 + c) * 136 + ki * 32 + quad * 8]);
#pragma unroll
          for (int ct = 0; ct < 4; ++ct)
            acc[ct] = __builtin_amdgcn_mfma_f32_16x16x32_bf16(a, bfrag[ct][ki], acc[ct], 0, 0, 0);
        }
#pragma unroll
        for (int ct = 0; ct < 4; ++ct) {
          int col = wl * 64 + ct * 16 + c;
#pragma unroll
          for (int r = 0; r < 4; ++r) {
            int row = rt * 16 + quad * 4 + r;
            sh_h[row * 264 + col] = bf_trunc(tanh_pre(acc[ct][r] + bias_c[ct]));
          }
        }
      }
    }
    __syncthreads();                            // barrier2

    if (rw == 0) {
      if (tid < 32)
        v0out[r0 + tid] = sh_v[tid * 4] + sh_v[tid * 4 + 1] + sh_v[tid * 4 + 2] +
                          sh_v[tid * 4 + 3] + vbias;
    } else if (wl < 2) {
      // ---- head GEMM over FULL K=256 for 16-row subtile st = wl,
      //      then in-register ratio epilogue (no sh_hb, no barrier3).
      const int st = wl;
      const int rrow = r0 + st * 16 + c;
      float4 act4 = *(const float4*)(action  + rrow * 8 + q2 * 4);
      float4 bt4  = *(const float4*)(beta_lp + rrow * 8 + q2 * 4);

      f32x4 acc2 = (f32x4){0.f, 0.f, 0.f, 0.f};
#pragma unroll
      for (int k2 = 0; k2 < 8; ++k2) {
        int kofs = k2 * 32 + quad * 8;
        short8 a2 = *(const short8*)(H1 + c * 256 + kofs);
        short8 b2 = *(const short8*)(&sh_h[(st * 16 + c) * 264 + kofs]);
        acc2 = __builtin_amdgcn_mfma_f32_16x16x32_bf16(a2, b2, acc2, 0, 0, 0);
      }
      // D-layout: out = quad*4+r (0-7 mu, 8-15 lv), sample = c.
      // quads 0,1 hold mu; matching lv sits at lane+32 -> shfl_xor(32).
      float sum = 0.f;
#pragma unroll
      for (int r = 0; r < 4; ++r) {
        float lv = __shfl_xor(acc2[r], 32) + ((const float*)&blv4)[r];
        float mu = acc2[r] + ((const float*)&bmu4)[r];
        float d  = ((const float*)&act4)[r] - mu;
        sum += -0.5f * d * d * __expf(-lv) - 0.5f * lv - HALF_LOG_2PI -
               ((const float*)&bt4)[r];
      }
      // fold a-halves: quad0 (a0-3) + quad1 (a4-7), same sample c
      sum += __int_as_float(
          __builtin_amdgcn_ds_swizzle(__float_as_int(sum), 0x401F));
      if (quad == 0) ratio[rrow] = __expf(sum);
    }
    // NOTE: no barrier3 — sh_h/sh_v reads above complete before next iter's
    // barrier1; their rewrite happens only after it.
  }
}

// ---------------------------------------------------------------- k_next:
// critic(next_state) -> v1. 2048 persistent blocks x NX_TPB tiles; 256 threads.
__global__ __launch_bounds__(256, 4) void k_next(
    const float* __restrict__ next_state,
    const unsigned short* __restrict__ Wc1Ts,
    const float* __restrict__ bc1, const float* __restrict__ Wc2,
    const float* __restrict__ bc2, float* __restrict__ v1out) {
  const int tid = threadIdx.x;
  const int lane = tid & 63;
  const int wv   = tid >> 6;
  const int c    = lane & 15;
  const int quad = lane >> 4;

  __shared__ unsigned short sh_x[32 * 136];
  __shared__ float sh_v[32 * 4];

  short8 bfrag[4][4];
  float bias_c[4], wc2_c[4];
#pragma unroll
  for (int ct = 0; ct < 4; ++ct) {
    int n = wv * 64 + ct * 16 + c;
    bias_c[ct] = bc1[n] * SCALE2;
    wc2_c[ct]  = Wc2[n];
#pragma unroll
    for (int ki = 0; ki < 4; ++ki)
      bfrag[ct][ki] = *(const short8*)(Wc1Ts + n * 128 + ki * 32 + quad * 8);
  }
  const float vbias = bc2[0];

  const int t0 = blockIdx.x * NX_TPB;
  float4 rbuf[4];
  {
    const float4* Xv = (const float4*)(next_state + (size_t)t0 * 32 * D_IN);
#pragma unroll
    for (int j = 0; j < 4; ++j) rbuf[j] = Xv[tid + j * 256];
  }

  for (int i = 0; i < NX_TPB; ++i) {
    const int r0 = (t0 + i) * 32;
#pragma unroll
    for (int j = 0; j < 4; ++j) {
      int e = tid + j * 256;
      int row = e >> 5, c4 = e & 31;
      uint2 u;
      u.x = pack_bf2(rbuf[j].x, rbuf[j].y);
      u.y = pack_bf2(rbuf[j].z, rbuf[j].w);
      *(uint2*)(&sh_x[row * 136 + c4 * 4]) = u;
    }
    __syncthreads();

    if (i + 1 < NX_TPB) {
      const float4* Xv2 = (const float4*)(next_state + (size_t)(r0 + 32) * D_IN);
#pragma unroll
      for (int j = 0; j < 4; ++j) rbuf[j] = Xv2[tid + j * 256];
    }

#pragma unroll
    for (int rt = 0; rt < 2; ++rt) {
      f32x4 acc[4];
#pragma unroll
      for (int ct = 0; ct < 4; ++ct) acc[ct] = (f32x4){0.f, 0.f, 0.f, 0.f};
#pragma unroll
      for (int ki = 0; ki < 4; ++ki) {
        short8 a = *(const short8*)(&sh_x[(rt * 16 + c) * 136 + ki * 32 + quad * 8]);
#pragma unroll
        for (int ct = 0; ct < 4; ++ct)
          acc[ct] = __builtin_amdgcn_mfma_f32_16x16x32_bf16(a, bfrag[ct][ki], acc[ct], 0, 0, 0);
      }
#pragma unroll
      for (int r = 0; r < 4; ++r) {
        float p = 0.f;
#pragma unroll
        for (int ct = 0; ct < 4; ++ct)
          p += tanh_pre(acc[ct][r] + bias_c[ct]) * wc2_c[ct];
        p = row16_sum(p);
        if (c == 15) sh_v[(rt * 16 + quad * 4 + r) * 4 + wv] = p;
      }
    }
    __syncthreads();
    if (tid < 32) {
      v1out[r0 + tid] = sh_v[tid * 4] + sh_v[tid * 4 + 1] + sh_v[tid * 4 + 2] +
                        sh_v[tid * 4 + 3] + vbias;
    }
  }
}

// ---------------------------------------------------------------- GAE + losses, ONE kernel:
// 256 blocks (== CU count -> guaranteed co-resident; software grid barrier via
// device-scope counters). Each block: 1024 own elems + 1024 lookahead
// (c^1024 ~ 5e-28 -> exact truncation in fp32). adv stays in registers.
// Spin is RELAXED (no per-iteration cache-invalidate); one ACQUIRE load after
// the condition is observed provides the synchronizes-with edge.
__global__ __launch_bounds__(256) void k_gae2(
    const float* __restrict__ reward, const float* __restrict__ v0,
    const float* __restrict__ v1, const float* __restrict__ ratio,
    float* __restrict__ accs, float* __restrict__ out) {
  const int j = blockIdx.x, k = threadIdx.x;
  const int base = j * 1024 + k * 8;
  unsigned int* cnt1 = (unsigned int*)accs + 4;
  unsigned int* cnt2 = (unsigned int*)accs + 5;

  float d[8];
  float s = 0.f, w = 1.f;
#pragma unroll
  for (int i = 0; i < 8; ++i) {
    int idx = base + i;
    float dd = 0.f;
    if (idx < T_N) dd = reward[idx] + GAMMA * v1[idx] - v0[idx];
    d[i] = dd;
    s += w * dd;
    w *= C_GL;
  }
  const float W8 = w;
  __shared__ float Ss[256], Sw[256];
  __shared__ float sh_stats[2];
  Ss[k] = s; Sw[k] = W8;
  __syncthreads();
  for (int st = 1; st < 256; st <<= 1) {
    bool has = (k + st) < 256;
    float ns = 0.f, nw = 0.f;
    if (has) { ns = Ss[k] + Sw[k] * Ss[k + st]; nw = Sw[k] * Sw[k + st]; }
    __syncthreads();
    if (has) { Ss[k] = ns; Sw[k] = nw; }
    __syncthreads();
  }
  float g = (k < 255) ? Ss[k + 1] : 0.f;
  float adv[8];
  float sa = 0.f, sq = 0.f;
  if (k < 128) {
#pragma unroll
    for (int i = 7; i >= 0; --i) {
      g = d[i] + C_GL * g;
      float a = g - v0[base + i];
      adv[i] = a;
      sa += a; sq += a * a;
    }
  }
  __syncthreads();
  Ss[k] = sa; Sw[k] = sq;
  __syncthreads();
  for (int off = 128; off > 0; off >>= 1) {
    if (k < off) { Ss[k] += Ss[k + off]; Sw[k] += Sw[k + off]; }
    __syncthreads();
  }
  if (k == 0) {
    atomicAdd(&accs[0], Ss[0]);                 // Σ adv
    atomicAdd(&accs[1], Sw[0]);                 // Σ adv² (= critic_loss)
    __hip_atomic_fetch_add(cnt1, 1u, __ATOMIC_RELEASE, __HIP_MEMORY_SCOPE_AGENT);
    // ---- software grid barrier (256 blocks co-resident on 256 CUs)
    while (__hip_atomic_load(cnt1, __ATOMIC_RELAXED, __HIP_MEMORY_SCOPE_AGENT) < 256u)
      __builtin_amdgcn_s_sleep(16);
    (void)__hip_atomic_load(cnt1, __ATOMIC_ACQUIRE, __HIP_MEMORY_SCOPE_AGENT);
    sh_stats[0] = __hip_atomic_load(&accs[0], __ATOMIC_RELAXED, __HIP_MEMORY_SCOPE_AGENT);
    sh_stats[1] = __hip_atomic_load(&accs[1], __ATOMIC_RELAXED, __HIP_MEMORY_SCOPE_AGENT);
  }
  __syncthreads();

  const float sum  = sh_stats[0];
  const float cl   = sh_stats[1];
  const float mean = sum * (1.f / (float)T_N);
  const float var  = (cl - sum * mean) / (float)(T_N - 1);
  const float inv  = 1.f / (sqrtf(var) + 1e-7f);
  float sl = 0.f;
  if (k < 128) {
#pragma unroll
    for (int i = 0; i < 8; ++i) {
      float a = (adv[i] - mean) * inv;
      float r = ratio[base + i];
      float rc = fminf(fmaxf(r, 1.f - EPS_C), 1.f + EPS_C);
      sl += -fminf(r * a, rc * a);
    }
  }
  __syncthreads();
  Ss[k] = sl;
  __syncthreads();
  for (int off = 128; off > 0; off >>= 1) {
    if (k < off) Ss[k] += Ss[k + off];
    __syncthreads();
  }
  if (k == 0) {
    atomicAdd(&accs[2], Ss[0]);                 // actor_loss
    unsigned int old = __hip_atomic_fetch_add(cnt2, 1u, __ATOMIC_ACQ_REL,
                                              __HIP_MEMORY_SCOPE_AGENT);
    if (old == 255u) {
      float al = __hip_atomic_load(&accs[2], __ATOMIC_RELAXED, __HIP_MEMORY_SCOPE_AGENT);
      out[0] = al + cl;                         // actor_loss + critic_loss
    }
  }
}

// ---------------------------------------------------------------- launch
extern "C" void kernel_launch(void* const* d_in, const int* in_sizes, int n_in,
                              void* d_out, int out_size, void* d_ws, size_t ws_size,
                              hipStream_t stream) {
  const float* state      = (const float*)d_in[0];
  const float* next_state = (const float*)d_in[1];
  const float* action     = (const float*)d_in[2];
  const float* beta_lp    = (const float*)d_in[3];
  const float* reward     = (const float*)d_in[4];
  const float* W1   = (const float*)d_in[5];
  const float* b1   = (const float*)d_in[6];
  const float* Wmu  = (const float*)d_in[7];
  const float* bmu  = (const float*)d_in[8];
  const float* Wlv  = (const float*)d_in[9];
  const float* blv  = (const float*)d_in[10];
  const float* Wc1  = (const float*)d_in[11];
  const float* bc1  = (const float*)d_in[12];
  const float* Wc2  = (const float*)d_in[13];
  const float* bc2  = (const float*)d_in[14];

  char* ws = (char*)d_ws;
  size_t o = 0;
  unsigned short* Wc1Ts = (unsigned short*)(ws + o); o += 65536;
  unsigned short* W1Ts  = (unsigned short*)(ws + o); o += 65536;
  unsigned short* H1    = (unsigned short*)(ws + o); o += 8192;
  float* v0    = (float*)(ws + o); o += (size_t)T_N * 4;
  float* v1    = (float*)(ws + o); o += (size_t)T_N * 4;
  float* ratio = (float*)(ws + o); o += (size_t)T_N * 4;
  float* accs  = (float*)(ws + o); o += 256;

  k_prep<<<272, 256, 0, stream>>>(Wc1, W1, Wmu, Wlv, Wc1Ts, W1Ts, H1, accs);

  k_state<<<(T_N / 32) / ST_TPB, 512, 0, stream>>>(
      state, action, beta_lp, Wc1Ts, W1Ts, H1, bc1, b1, Wc2, bc2, bmu, blv,
      v0, ratio);
  k_next<<<(T_N / 32) / NX_TPB, 256, 0, stream>>>(
      next_state, Wc1Ts, bc1, Wc2, bc2, v1);
  k_gae2<<<256, 256, 0, stream>>>(reward, v0, v1, ratio, accs, (float*)d_out);
}

// Round 9
// 374.055 us; speedup vs baseline: 1.3198x; 1.1196x over previous
//
#include <hip/hip_runtime.h>

// ---------------------------------------------------------------- constants
#define T_N   262144
#define D_IN  128
#define A_DIM 8
#define GAMMA 0.99f
#define EPS_C 0.2f
#define C_GL  0.9405f                 // GAMMA*LMBD
#define HALF_LOG_2PI 0.9189385332f
#define SCALE2 2.8853900817779268f    // 2*log2(e): pre-activation scale for exp2-tanh
#define ST_TPB 8                      // k_state tiles/block -> 1024 blocks (4/CU)
#define NX_TPB 4                      // k_next tiles/block  -> 2048 blocks (8/CU)
#define HB_S   20                     // sh_hb padded stride (floats)

typedef __attribute__((ext_vector_type(8))) short short8;
typedef __attribute__((ext_vector_type(4))) float f32x4;

__device__ __forceinline__ unsigned short f2bf(float f) {   // RNE (prep only)
  unsigned int u = __float_as_uint(f);
  u += 0x7FFFu + ((u >> 16) & 1u);
  return (unsigned short)(u >> 16);
}
// pack two f32 -> two bf16 (truncate) in ONE v_perm_b32
__device__ __forceinline__ unsigned int pack_bf2(float lo, float hi) {
  return __builtin_amdgcn_perm(__float_as_uint(hi), __float_as_uint(lo), 0x07060302u);
}
__device__ __forceinline__ unsigned short bf_trunc(float f) {
  return (unsigned short)(__float_as_uint(f) >> 16);
}
// a = 2*log2(e)*x (weights pre-scaled); returns tanh(x).
__device__ __forceinline__ float tanh_pre(float a) {
  float e = __builtin_amdgcn_exp2f(a);
  return 1.f - 2.f * __builtin_amdgcn_rcpf(e + 1.f);
}
template <int CTRL>
__device__ __forceinline__ float dpp_add(float p) {
  return p + __int_as_float(__builtin_amdgcn_update_dpp(
                 0, __float_as_int(p), CTRL, 0xF, 0xF, true));
}
// sum over each 16-lane row; total lands at lane%16 == 15
__device__ __forceinline__ float row16_sum(float p) {
  p = dpp_add<0x111>(p); p = dpp_add<0x112>(p);
  p = dpp_add<0x114>(p); p = dpp_add<0x118>(p);
  return p;
}
// sum over each 8-lane group; total at all 8 lanes (xor1, xor2, half-mirror)
__device__ __forceinline__ float xor8_sum(float p) {
  p = dpp_add<0xB1>(p); p = dpp_add<0x4E>(p); p = dpp_add<0x141>(p);
  return p;
}

// ---------------------------------------------------------------- prep:
// Wc1Ts/W1Ts: [H][D] bf16, transposed AND pre-scaled by 2*log2(e).
// H1: [16][256] bf16 actor head (rows0-7 = Wmu^T, 8-15 = Wlv^T). Also zeros accs.
__global__ __launch_bounds__(256) void k_prep(
    const float* __restrict__ Wc1, const float* __restrict__ W1,
    const float* __restrict__ Wmu, const float* __restrict__ Wlv,
    unsigned short* __restrict__ Wc1Ts, unsigned short* __restrict__ W1Ts,
    unsigned short* __restrict__ H1, float* __restrict__ accs) {
  int i = blockIdx.x * 256 + threadIdx.x;
  if (blockIdx.x == 0 && threadIdx.x < 8) ((unsigned int*)accs)[threadIdx.x] = 0u;
  if (i < 32768) {
    int n = i >> 7, k = i & 127;
    Wc1Ts[i] = f2bf(Wc1[k * 256 + n] * SCALE2);
  } else if (i < 65536) {
    int j = i - 32768; int n = j >> 7, k = j & 127;
    W1Ts[j] = f2bf(W1[k * 256 + n] * SCALE2);
  } else if (i < 69632) {
    int j = i - 65536; int h = j >> 8, n = j & 255;
    H1[j] = (h < 8) ? f2bf(Wmu[n * 8 + h]) : f2bf(Wlv[n * 8 + (h - 8)]);
  }
}

// ---------------------------------------------------------------- k_state:
// R0-exact structure (measured 92 us): 1024 persistent blocks x ST_TPB tiles
// of 32 rows; 512 threads. waves 0-3: critic(state)->v0 (64-col slices, fused
// VALU head); waves 4-7: actor(state) hidden -> head MFMA (4-way K-split) ->
// sh_hb -> 256-thread ratio epilogue on critic waves. 3 barriers/tile.
// Role balance: ratio epilogue runs on critic waves; action/beta loads issued
// EARLY (before GEMM) to hide cold-HBM latency. Both properties measured
// essential (R7: concentrating head+epilogue+loads on 2 waves cost +52 us).
__global__ __launch_bounds__(512, 4) void k_state(
    const float* __restrict__ state,
    const float* __restrict__ action, const float* __restrict__ beta_lp,
    const unsigned short* __restrict__ Wc1Ts, const unsigned short* __restrict__ W1Ts,
    const unsigned short* __restrict__ H1,
    const float* __restrict__ bc1, const float* __restrict__ b1,
    const float* __restrict__ Wc2, const float* __restrict__ bc2,
    const float* __restrict__ bmu, const float* __restrict__ blv,
    float* __restrict__ v0out, float* __restrict__ ratio) {
  const int tid  = threadIdx.x;
  const int lane = tid & 63;
  const int wv   = tid >> 6;          // 0..7
  const int role = wv >> 2;           // 0 = critic, 1 = actor
  const int wl   = wv & 3;            // slice within role
  const int c    = lane & 15;
  const int quad = lane >> 4;

  __shared__ unsigned short sh_x[32 * 136];   // 8.5 KB
  __shared__ unsigned short sh_h[32 * 264];   // 16.5 KB
  __shared__ float sh_hb[4 * 32 * HB_S];      // 10 KB, padded stride
  __shared__ float sh_v[32 * 4];

  const unsigned short* WT = role ? W1Ts : Wc1Ts;
  const float* bias = role ? b1 : bc1;

  short8 bfrag[4][4];
  float bias_c[4], wc2_c[4];
#pragma unroll
  for (int ct = 0; ct < 4; ++ct) {
    int n = wl * 64 + ct * 16 + c;
    bias_c[ct] = bias[n] * SCALE2;
    wc2_c[ct]  = Wc2[n];
#pragma unroll
    for (int ki = 0; ki < 4; ++ki)
      bfrag[ct][ki] = *(const short8*)(WT + n * 128 + ki * 32 + quad * 8);
  }
  const float vbias = bc2[0];
  const int aa = tid & 7;
  const float bmu_a = bmu[aa], blv_a = blv[aa];

  const int t0 = blockIdx.x * ST_TPB;

  float4 rbuf[2];
  {
    const float4* Xv = (const float4*)(state + (size_t)t0 * 32 * D_IN);
    rbuf[0] = Xv[tid]; rbuf[1] = Xv[tid + 512];
  }

  for (int i = 0; i < ST_TPB; ++i) {
    const int r0 = (t0 + i) * 32;

    // ---- stage regs -> LDS bf16 (perm-truncate: 1 op / 2 elems)
#pragma unroll
    for (int j = 0; j < 2; ++j) {
      int e4 = tid + j * 512;
      int row = e4 >> 5, c4 = e4 & 31;
      uint2 u;
      u.x = pack_bf2(rbuf[j].x, rbuf[j].y);
      u.y = pack_bf2(rbuf[j].z, rbuf[j].w);
      *(uint2*)(&sh_x[row * 136 + c4 * 4]) = u;
    }
    __syncthreads();                            // barrier1

    if (i + 1 < ST_TPB) {
      const float4* Xv2 = (const float4*)(state + (size_t)(r0 + 32) * D_IN);
      rbuf[0] = Xv2[tid]; rbuf[1] = Xv2[tid + 512];
    }
    float fa = 0.f, fb = 0.f;
    if (tid < 256) { fa = action[r0 * 8 + tid]; fb = beta_lp[r0 * 8 + tid]; }

    if (role == 0) {
      // ---- critic GEMM + fused head
#pragma unroll
      for (int rt = 0; rt < 2; ++rt) {
        f32x4 acc[4];
#pragma unroll
        for (int ct = 0; ct < 4; ++ct) acc[ct] = (f32x4){0.f, 0.f, 0.f, 0.f};
#pragma unroll
        for (int ki = 0; ki < 4; ++ki) {
          short8 a = *(const short8*)(&sh_x[(rt * 16 + c) * 136 + ki * 32 + quad * 8]);
#pragma unroll
          for (int ct = 0; ct < 4; ++ct)
            acc[ct] = __builtin_amdgcn_mfma_f32_16x16x32_bf16(a, bfrag[ct][ki], acc[ct], 0, 0, 0);
        }
#pragma unroll
        for (int r = 0; r < 4; ++r) {
          float p = 0.f;
#pragma unroll
          for (int ct = 0; ct < 4; ++ct)
            p += tanh_pre(acc[ct][r] + bias_c[ct]) * wc2_c[ct];
          p = row16_sum(p);
          if (c == 15) sh_v[(rt * 16 + quad * 4 + r) * 4 + wl] = p;
        }
      }
    } else {
      // ---- actor GEMM -> sh_h
#pragma unroll
      for (int rt = 0; rt < 2; ++rt) {
        f32x4 acc[4];
#pragma unroll
        for (int ct = 0; ct < 4; ++ct) acc[ct] = (f32x4){0.f, 0.f, 0.f, 0.f};
#pragma unroll
        for (int ki = 0; ki < 4; ++ki) {
          short8 a = *(const short8*)(&sh_x[(rt * 16 + c) * 136 + ki * 32 + quad * 8]);
#pragma unroll
          for (int ct = 0; ct < 4; ++ct)
            acc[ct] = __builtin_amdgcn_mfma_f32_16x16x32_bf16(a, bfrag[ct][ki], acc[ct], 0, 0, 0);
        }
#pragma unroll
        for (int ct = 0; ct < 4; ++ct) {
          int col = wl * 64 + ct * 16 + c;
#pragma unroll
          for (int r = 0; r < 4; ++r) {
            int row = rt * 16 + quad * 4 + r;
            sh_h[row * 264 + col] = bf_trunc(tanh_pre(acc[ct][r] + bias_c[ct]));
          }
        }
      }
    }
    __syncthreads();                            // barrier2

    if (role == 1) {
      // ---- head GEMM: slice wl owns K-cols [wl*64, +64)
#pragma unroll
      for (int st = 0; st < 2; ++st) {
        f32x4 acc2 = (f32x4){0.f, 0.f, 0.f, 0.f};
#pragma unroll
        for (int k2 = 0; k2 < 2; ++k2) {
          int kofs = wl * 64 + k2 * 32 + quad * 8;
          short8 a2 = *(const short8*)(H1 + c * 256 + kofs);
          short8 b2 = *(const short8*)(&sh_h[(st * 16 + c) * 264 + kofs]);
          acc2 = __builtin_amdgcn_mfma_f32_16x16x32_bf16(a2, b2, acc2, 0, 0, 0);
        }
        *((f32x4*)&sh_hb[((wl * 32) + st * 16 + c) * HB_S + quad * 4]) = acc2;
      }
    } else if (tid < 32) {
      v0out[r0 + tid] = sh_v[tid * 4] + sh_v[tid * 4 + 1] + sh_v[tid * 4 + 2] +
                        sh_v[tid * 4 + 3] + vbias;
    }
    __syncthreads();                            // barrier3

    if (tid < 256) {
      int s = tid >> 3;
      float mu = sh_hb[(s)*HB_S + aa]            + sh_hb[(32 + s) * HB_S + aa] +
                 sh_hb[(64 + s) * HB_S + aa]     + sh_hb[(96 + s) * HB_S + aa] + bmu_a;
      float lv = sh_hb[(s)*HB_S + 8 + aa]        + sh_hb[(32 + s) * HB_S + 8 + aa] +
                 sh_hb[(64 + s) * HB_S + 8 + aa] + sh_hb[(96 + s) * HB_S + 8 + aa] + blv_a;
      float d = fa - mu;
      float term = -0.5f * d * d * __expf(-lv) - 0.5f * lv - HALF_LOG_2PI - fb;
      term = xor8_sum(term);
      if (aa == 0) ratio[r0 + s] = __expf(term);
    }
  }
}

// ---------------------------------------------------------------- k_next:
// critic(next_state) -> v1. 2048 persistent blocks x NX_TPB tiles; 256 threads.
__global__ __launch_bounds__(256, 4) void k_next(
    const float* __restrict__ next_state,
    const unsigned short* __restrict__ Wc1Ts,
    const float* __restrict__ bc1, const float* __restrict__ Wc2,
    const float* __restrict__ bc2, float* __restrict__ v1out) {
  const int tid = threadIdx.x;
  const int lane = tid & 63;
  const int wv   = tid >> 6;
  const int c    = lane & 15;
  const int quad = lane >> 4;

  __shared__ unsigned short sh_x[32 * 136];
  __shared__ float sh_v[32 * 4];

  short8 bfrag[4][4];
  float bias_c[4], wc2_c[4];
#pragma unroll
  for (int ct = 0; ct < 4; ++ct) {
    int n = wv * 64 + ct * 16 + c;
    bias_c[ct] = bc1[n] * SCALE2;
    wc2_c[ct]  = Wc2[n];
#pragma unroll
    for (int ki = 0; ki < 4; ++ki)
      bfrag[ct][ki] = *(const short8*)(Wc1Ts + n * 128 + ki * 32 + quad * 8);
  }
  const float vbias = bc2[0];

  const int t0 = blockIdx.x * NX_TPB;
  float4 rbuf[4];
  {
    const float4* Xv = (const float4*)(next_state + (size_t)t0 * 32 * D_IN);
#pragma unroll
    for (int j = 0; j < 4; ++j) rbuf[j] = Xv[tid + j * 256];
  }

  for (int i = 0; i < NX_TPB; ++i) {
    const int r0 = (t0 + i) * 32;
#pragma unroll
    for (int j = 0; j < 4; ++j) {
      int e = tid + j * 256;
      int row = e >> 5, c4 = e & 31;
      uint2 u;
      u.x = pack_bf2(rbuf[j].x, rbuf[j].y);
      u.y = pack_bf2(rbuf[j].z, rbuf[j].w);
      *(uint2*)(&sh_x[row * 136 + c4 * 4]) = u;
    }
    __syncthreads();

    if (i + 1 < NX_TPB) {
      const float4* Xv2 = (const float4*)(next_state + (size_t)(r0 + 32) * D_IN);
#pragma unroll
      for (int j = 0; j < 4; ++j) rbuf[j] = Xv2[tid + j * 256];
    }

#pragma unroll
    for (int rt = 0; rt < 2; ++rt) {
      f32x4 acc[4];
#pragma unroll
      for (int ct = 0; ct < 4; ++ct) acc[ct] = (f32x4){0.f, 0.f, 0.f, 0.f};
#pragma unroll
      for (int ki = 0; ki < 4; ++ki) {
        short8 a = *(const short8*)(&sh_x[(rt * 16 + c) * 136 + ki * 32 + quad * 8]);
#pragma unroll
        for (int ct = 0; ct < 4; ++ct)
          acc[ct] = __builtin_amdgcn_mfma_f32_16x16x32_bf16(a, bfrag[ct][ki], acc[ct], 0, 0, 0);
      }
#pragma unroll
      for (int r = 0; r < 4; ++r) {
        float p = 0.f;
#pragma unroll
        for (int ct = 0; ct < 4; ++ct)
          p += tanh_pre(acc[ct][r] + bias_c[ct]) * wc2_c[ct];
        p = row16_sum(p);
        if (c == 15) sh_v[(rt * 16 + quad * 4 + r) * 4 + wv] = p;
      }
    }
    __syncthreads();
    if (tid < 32) {
      v1out[r0 + tid] = sh_v[tid * 4] + sh_v[tid * 4 + 1] + sh_v[tid * 4 + 2] +
                        sh_v[tid * 4 + 3] + vbias;
    }
  }
}

// ---------------------------------------------------------------- GAE + losses, ONE kernel:
// 256 blocks (== CU count -> guaranteed co-resident; software grid barrier via
// device-scope counters). Each block: 1024 own elems + 1024 lookahead
// (c^1024 ~ 5e-28 -> exact truncation in fp32). adv stays in registers.
// Spin is RELAXED (no per-iteration cache-invalidate); one ACQUIRE load after
// the condition is observed provides the synchronizes-with edge.
__global__ __launch_bounds__(256) void k_gae2(
    const float* __restrict__ reward, const float* __restrict__ v0,
    const float* __restrict__ v1, const float* __restrict__ ratio,
    float* __restrict__ accs, float* __restrict__ out) {
  const int j = blockIdx.x, k = threadIdx.x;
  const int base = j * 1024 + k * 8;
  unsigned int* cnt1 = (unsigned int*)accs + 4;
  unsigned int* cnt2 = (unsigned int*)accs + 5;

  float d[8];
  float s = 0.f, w = 1.f;
#pragma unroll
  for (int i = 0; i < 8; ++i) {
    int idx = base + i;
    float dd = 0.f;
    if (idx < T_N) dd = reward[idx] + GAMMA * v1[idx] - v0[idx];
    d[i] = dd;
    s += w * dd;
    w *= C_GL;
  }
  const float W8 = w;
  __shared__ float Ss[256], Sw[256];
  __shared__ float sh_stats[2];
  Ss[k] = s; Sw[k] = W8;
  __syncthreads();
  for (int st = 1; st < 256; st <<= 1) {
    bool has = (k + st) < 256;
    float ns = 0.f, nw = 0.f;
    if (has) { ns = Ss[k] + Sw[k] * Ss[k + st]; nw = Sw[k] * Sw[k + st]; }
    __syncthreads();
    if (has) { Ss[k] = ns; Sw[k] = nw; }
    __syncthreads();
  }
  float g = (k < 255) ? Ss[k + 1] : 0.f;
  float adv[8];
  float sa = 0.f, sq = 0.f;
  if (k < 128) {
#pragma unroll
    for (int i = 7; i >= 0; --i) {
      g = d[i] + C_GL * g;
      float a = g - v0[base + i];
      adv[i] = a;
      sa += a; sq += a * a;
    }
  }
  __syncthreads();
  Ss[k] = sa; Sw[k] = sq;
  __syncthreads();
  for (int off = 128; off > 0; off >>= 1) {
    if (k < off) { Ss[k] += Ss[k + off]; Sw[k] += Sw[k + off]; }
    __syncthreads();
  }
  if (k == 0) {
    atomicAdd(&accs[0], Ss[0]);                 // Σ adv
    atomicAdd(&accs[1], Sw[0]);                 // Σ adv² (= critic_loss)
    __hip_atomic_fetch_add(cnt1, 1u, __ATOMIC_RELEASE, __HIP_MEMORY_SCOPE_AGENT);
    // ---- software grid barrier (256 blocks co-resident on 256 CUs)
    while (__hip_atomic_load(cnt1, __ATOMIC_RELAXED, __HIP_MEMORY_SCOPE_AGENT) < 256u)
      __builtin_amdgcn_s_sleep(16);
    (void)__hip_atomic_load(cnt1, __ATOMIC_ACQUIRE, __HIP_MEMORY_SCOPE_AGENT);
    sh_stats[0] = __hip_atomic_load(&accs[0], __ATOMIC_RELAXED, __HIP_MEMORY_SCOPE_AGENT);
    sh_stats[1] = __hip_atomic_load(&accs[1], __ATOMIC_RELAXED, __HIP_MEMORY_SCOPE_AGENT);
  }
  __syncthreads();

  const float sum  = sh_stats[0];
  const float cl   = sh_stats[1];
  const float mean = sum * (1.f / (float)T_N);
  const float var  = (cl - sum * mean) / (float)(T_N - 1);
  const float inv  = 1.f / (sqrtf(var) + 1e-7f);
  float sl = 0.f;
  if (k < 128) {
#pragma unroll
    for (int i = 0; i < 8; ++i) {
      float a = (adv[i] - mean) * inv;
      float r = ratio[base + i];
      float rc = fminf(fmaxf(r, 1.f - EPS_C), 1.f + EPS_C);
      sl += -fminf(r * a, rc * a);
    }
  }
  __syncthreads();
  Ss[k] = sl;
  __syncthreads();
  for (int off = 128; off > 0; off >>= 1) {
    if (k < off) Ss[k] += Ss[k + off];
    __syncthreads();
  }
  if (k == 0) {
    atomicAdd(&accs[2], Ss[0]);                 // actor_loss
    unsigned int old = __hip_atomic_fetch_add(cnt2, 1u, __ATOMIC_ACQ_REL,
                                              __HIP_MEMORY_SCOPE_AGENT);
    if (old == 255u) {
      float al = __hip_atomic_load(&accs[2], __ATOMIC_RELAXED, __HIP_MEMORY_SCOPE_AGENT);
      out[0] = al + cl;                         // actor_loss + critic_loss
    }
  }
}

// ---------------------------------------------------------------- launch
extern "C" void kernel_launch(void* const* d_in, const int* in_sizes, int n_in,
                              void* d_out, int out_size, void* d_ws, size_t ws_size,
                              hipStream_t stream) {
  const float* state      = (const float*)d_in[0];
  const float* next_state = (const float*)d_in[1];
  const float* action     = (const float*)d_in[2];
  const float* beta_lp    = (const float*)d_in[3];
  const float* reward     = (const float*)d_in[4];
  const float* W1   = (const float*)d_in[5];
  const float* b1   = (const float*)d_in[6];
  const float* Wmu  = (const float*)d_in[7];
  const float* bmu  = (const float*)d_in[8];
  const float* Wlv  = (const float*)d_in[9];
  const float* blv  = (const float*)d_in[10];
  const float* Wc1  = (const float*)d_in[11];
  const float* bc1  = (const float*)d_in[12];
  const float* Wc2  = (const float*)d_in[13];
  const float* bc2  = (const float*)d_in[14];

  char* ws = (char*)d_ws;
  size_t o = 0;
  unsigned short* Wc1Ts = (unsigned short*)(ws + o); o += 65536;
  unsigned short* W1Ts  = (unsigned short*)(ws + o); o += 65536;
  unsigned short* H1    = (unsigned short*)(ws + o); o += 8192;
  float* v0    = (float*)(ws + o); o += (size_t)T_N * 4;
  float* v1    = (float*)(ws + o); o += (size_t)T_N * 4;
  float* ratio = (float*)(ws + o); o += (size_t)T_N * 4;
  float* accs  = (float*)(ws + o); o += 256;

  k_prep<<<272, 256, 0, stream>>>(Wc1, W1, Wmu, Wlv, Wc1Ts, W1Ts, H1, accs);

  k_state<<<(T_N / 32) / ST_TPB, 512, 0, stream>>>(
      state, action, beta_lp, Wc1Ts, W1Ts, H1, bc1, b1, Wc2, bc2, bmu, blv,
      v0, ratio);
  k_next<<<(T_N / 32) / NX_TPB, 256, 0, stream>>>(
      next_state, Wc1Ts, bc1, Wc2, bc2, v1);
  k_gae2<<<256, 256, 0, stream>>>(reward, v0, v1, ratio, accs, (float*)d_out);
}